// Round 2
// baseline (57.948 us; speedup 1.0000x reference)
//
#include <hip/hip_runtime.h>

// Problem constants (from reference)
constexpr int Bn = 8, Hn = 1536, Wn = 2048;
constexpr int NUM_GTS = 64;
constexpr float INV_N = 1.0f / (float)((long long)Bn * Hn * Wn);

// One thread = 4 consecutive columns of one row, across all 8 batch planes.
// 512 threads per row -> each 64-lane wave lies in a single row, so a single
// __ballot (lane i tests box i's row interval) yields the per-row active-box
// bitmask for the whole wave.
//
// Key change vs prev round: issue ALL 8 plane loads into registers before
// consuming any (MLP 1 -> 8). Prev kernel had VGPR=20 -> fully serialized
// load->use chains -> latency-bound at 1.65 TB/s effective.
__global__ __launch_bounds__(256) void depth_loss_kernel(
    const float* __restrict__ depth,
    const int*   __restrict__ bbox,
    float*       __restrict__ out)
{
    __shared__ int s_tlx[NUM_GTS], s_tly[NUM_GTS], s_brx[NUM_GTS], s_bry[NUM_GTS];
    const int tid = threadIdx.x;
    if (tid < NUM_GTS) {
        s_tlx[tid] = bbox[tid * 4 + 0];
        s_tly[tid] = bbox[tid * 4 + 1];
        s_brx[tid] = bbox[tid * 4 + 2];
        s_bry[tid] = bbox[tid * 4 + 3];
    }
    __syncthreads();

    const int gid  = blockIdx.x * 256 + tid;     // pixel-group id, [0, 786432)
    const int r    = gid >> 9;                   // / 512 groups per row
    const int c0   = (gid & 511) << 2;           // * 4 columns per group
    const int lane = tid & 63;

    // Issue all 8 plane loads first: 8 outstanding vmem ops per wave.
    // 32-bit indexing: max index 25.2M < 2^31.
    const int base = r * Wn + c0;
    constexpr int plane = Hn * Wn;
    float4 v[Bn];
#pragma unroll
    for (int b = 0; b < Bn; ++b)
        v[b] = *reinterpret_cast<const float4*>(depth + (base + b * plane));

    // Row-interval test for box = lane; ballot -> per-row 64-box mask.
    // (Runs while the loads are in flight.)
    const bool rowhit = (r >= s_tly[lane] - 1) && (r < s_bry[lane]);
    unsigned long long rowm = __ballot(rowhit);

    // Column check only for boxes active in this row (~7 avg, wave-uniform loop).
    unsigned tbits = 0u;
    while (rowm) {
        const int i = __ffsll((long long)rowm) - 1;
        rowm &= rowm - 1;
        int lo = s_tlx[i] - 1 - c0;
        int hi = s_brx[i] - c0;
        lo = lo < 0 ? 0 : lo;
        hi = hi > 4 ? 4 : hi;
        if (lo < hi) tbits |= ((1u << hi) - (1u << lo));
    }
    // Per-column sign: +1 if target 0, -1 if target 1.
    float sgn[4];
#pragma unroll
    for (int j = 0; j < 4; ++j)
        sgn[j] = (tbits & (1u << j)) ? -1.0f : 1.0f;

    // Focal loss: x = sgn*(1-2p); e=exp(x); l=log1p(e); pt=1/(1+e);
    // acc += (1-pt)^2 * l
    float acc = 0.0f;
#pragma unroll
    for (int b = 0; b < Bn; ++b) {
        const float pv[4] = {v[b].x, v[b].y, v[b].z, v[b].w};
#pragma unroll
        for (int j = 0; j < 4; ++j) {
            const float x  = sgn[j] * (1.0f - 2.0f * pv[j]);
            const float e  = __expf(x);
            const float l  = __logf(1.0f + e);   // 1+e in [1.37, 3.72]
            const float pt = 1.0f / (1.0f + e);
            const float om = 1.0f - pt;
            acc += om * om * l;
        }
    }

    // Wave reduce (64 lanes), then block reduce, one atomic per block.
#pragma unroll
    for (int off = 32; off > 0; off >>= 1)
        acc += __shfl_down(acc, off, 64);

    __shared__ float s_part[4];
    const int w = tid >> 6;
    if (lane == 0) s_part[w] = acc;
    __syncthreads();
    if (tid == 0) {
        const float s = s_part[0] + s_part[1] + s_part[2] + s_part[3];
        atomicAdd(out, s * INV_N);              // LOSS_WEIGHT = 1
    }
}

extern "C" void kernel_launch(void* const* d_in, const int* in_sizes, int n_in,
                              void* d_out, int out_size, void* d_ws, size_t ws_size,
                              hipStream_t stream) {
    const float* depth = (const float*)d_in[0];
    const int*   bbox  = (const int*)d_in[1];
    float*       out   = (float*)d_out;

    hipMemsetAsync(d_out, 0, sizeof(float), stream);

    const int groups = (Hn * Wn) / 4;           // 786432 pixel groups
    const int blocks = groups / 256;            // 3072
    depth_loss_kernel<<<blocks, 256, 0, stream>>>(depth, bbox, out);
}

// Round 3
// 28.393 us; speedup vs baseline: 2.0409x; 2.0409x over previous
//
#include <hip/hip_runtime.h>

// Problem constants (from reference)
constexpr int Bn = 8, Hn = 1536, Wn = 2048;
constexpr int NUM_GTS = 64;
constexpr int PLANE   = Hn * Wn;            // 3145728 elements per batch plane
constexpr int GROUPS  = PLANE / 4;          // 786432 groups of 4 columns
constexpr int BLOCKS  = 1024;               // 4 blocks/CU -> fully resident, no tail
constexpr int GSTRIDE = BLOCKS * 256;       // 262144 threads; 3 groups per thread
constexpr float INV_N = 1.0f / (float)((long long)Bn * PLANE);

// Per-element focal term: x = sgn*(1-2p); softplus(x) * sigmoid(x)^2.
// Division replaced by v_rcp_f32 (1 ulp; output threshold is 4.7e-3).
__device__ __forceinline__ float focal_term(float p, float m2s, float sgn) {
    const float x  = __builtin_fmaf(m2s, p, sgn);   // sgn*(1-2p), single FMA
    const float e  = __expf(x);
    const float t  = 1.0f + e;
    const float l  = __logf(t);                     // softplus(x) = -logpt_t
    const float r  = __builtin_amdgcn_rcpf(t);
    const float om = e * r;                         // 1-pt = sigmoid(x)
    return om * om * l;
}

// Column-mask for one pixel-group. Wave lies in a single row, so lane i tests
// box i's row interval and one ballot gives the per-row active-box mask.
__device__ __forceinline__ unsigned group_tbits(int r, int c0, int tly, int bry,
                                                const int* s_tlx, const int* s_brx) {
    const bool rowhit = (r >= tly - 1) && (r < bry);
    unsigned long long rowm = __ballot(rowhit);
    unsigned tb = 0u;
    while (rowm) {
        const int i = __ffsll((unsigned long long)rowm) - 1;
        rowm &= rowm - 1;
        int lo = s_tlx[i] - 1 - c0;
        int hi = s_brx[i] - c0;
        lo = lo < 0 ? 0 : lo;
        hi = hi > 4 ? 4 : hi;
        if (lo < hi) tb |= ((1u << hi) - (1u << lo));
    }
    return tb;
}

// Sum the 32 elements (8 planes x 4 cols) of one group held in registers.
__device__ __forceinline__ float group_sum(const float4* v, unsigned tb) {
    float sgn[4], m2s[4];
#pragma unroll
    for (int j = 0; j < 4; ++j) {
        sgn[j] = (tb & (1u << j)) ? -1.0f : 1.0f;
        m2s[j] = -2.0f * sgn[j];
    }
    float a = 0.0f;
#pragma unroll
    for (int b = 0; b < Bn; ++b) {
        a += focal_term(v[b].x, m2s[0], sgn[0]);
        a += focal_term(v[b].y, m2s[1], sgn[1]);
        a += focal_term(v[b].z, m2s[2], sgn[2]);
        a += focal_term(v[b].w, m2s[3], sgn[3]);
    }
    return a;
}

#define LOADG(dst, gid)                                                        \
    do {                                                                       \
        const int _base = ((gid) >> 9) * Wn + (((gid) & 511) << 2);            \
        _Pragma("unroll")                                                      \
        for (int _b = 0; _b < Bn; ++_b)                                        \
            dst[_b] = *reinterpret_cast<const float4*>(depth + _base + _b * PLANE); \
    } while (0)

__global__ __launch_bounds__(256) void depth_loss_kernel(
    const float* __restrict__ depth,
    const int*   __restrict__ bbox,
    float*       __restrict__ ws)
{
    __shared__ int s_tlx[NUM_GTS], s_brx[NUM_GTS];
    const int tid = threadIdx.x;
    if (tid < NUM_GTS) {
        s_tlx[tid] = bbox[tid * 4 + 0];
        s_brx[tid] = bbox[tid * 4 + 2];
    }
    __syncthreads();

    const int lane = tid & 63;
    const int tly  = bbox[lane * 4 + 1];    // per-lane own box, for the ballot
    const int bry  = bbox[lane * 4 + 3];

    const int g0 = blockIdx.x * 256 + tid;
    const int g1 = g0 + GSTRIDE;
    const int g2 = g1 + GSTRIDE;

    // Software pipeline: two register tile buffers, 16 loads in flight at peak.
    float4 A[Bn], Bv[Bn];
    LOADG(A, g0);
    LOADG(Bv, g1);

    const unsigned tb0 = group_tbits(g0 >> 9, (g0 & 511) << 2, tly, bry, s_tlx, s_brx);
    const unsigned tb1 = group_tbits(g1 >> 9, (g1 & 511) << 2, tly, bry, s_tlx, s_brx);
    const unsigned tb2 = group_tbits(g2 >> 9, (g2 & 511) << 2, tly, bry, s_tlx, s_brx);

    float acc = group_sum(A, tb0);          // Bv in flight during this
    LOADG(A, g2);
    acc += group_sum(Bv, tb1);              // A(g2) in flight during this
    acc += group_sum(A, tb2);

    // Wave reduce (64 lanes), then block reduce, one ws write per block.
#pragma unroll
    for (int off = 32; off > 0; off >>= 1)
        acc += __shfl_down(acc, off, 64);

    __shared__ float s_part[4];
    if (lane == 0) s_part[tid >> 6] = acc;
    __syncthreads();
    if (tid == 0)
        ws[blockIdx.x] = s_part[0] + s_part[1] + s_part[2] + s_part[3];
}

__global__ __launch_bounds__(256) void reduce_kernel(
    const float* __restrict__ ws,
    float*       __restrict__ out)
{
    const int tid = threadIdx.x;
    float s = ws[tid] + ws[tid + 256] + ws[tid + 512] + ws[tid + 768];
#pragma unroll
    for (int off = 32; off > 0; off >>= 1)
        s += __shfl_down(s, off, 64);

    __shared__ float s_part[4];
    if ((tid & 63) == 0) s_part[tid >> 6] = s;
    __syncthreads();
    if (tid == 0)
        out[0] = (s_part[0] + s_part[1] + s_part[2] + s_part[3]) * INV_N;
}

extern "C" void kernel_launch(void* const* d_in, const int* in_sizes, int n_in,
                              void* d_out, int out_size, void* d_ws, size_t ws_size,
                              hipStream_t stream) {
    const float* depth = (const float*)d_in[0];
    const int*   bbox  = (const int*)d_in[1];
    float*       out   = (float*)d_out;
    float*       ws    = (float*)d_ws;

    depth_loss_kernel<<<BLOCKS, 256, 0, stream>>>(depth, bbox, ws);
    reduce_kernel<<<1, 256, 0, stream>>>(ws, out);
}